// Round 16
// baseline (166.267 us; speedup 1.0000x reference)
//
#include <hip/hip_runtime.h>
#include <hip/hip_cooperative_groups.h>
#include <hip/hip_bf16.h>
#include <math.h>

namespace cg = cooperative_groups;

#define N_PROP 600
#define NUM_CLS 151
#define FEAT_DIM 4096
#define K_OUT 100
#define SCORE_THRESH 0.05f
#define NMS_THRESH 0.5f
#define PER_CLS_TOPN 300
#define IMG_W 1024.0f
#define IMG_H 768.0f
#define BBOX_CLIP 4.135166556742356f  /* log(1000/16) */
#define MAXW 10                       /* ceil(600/64) */
#define NBLK 200                      /* grid: 100 feat rows + 100 bpc rows */

// out layout (reference return order, all f32):
#define OF_BOX (K_OUT * FEAT_DIM)      /* 409600: final_boxes [100,4]   */
#define OF_SC  (OF_BOX + K_OUT * 4)    /* 410000: final_scores [100]    */
#define OF_LB  (OF_SC + K_OUT)         /* 410100: final_labels [100]    */
#define OF_VD  (OF_LB + K_OUT)         /* 410200: valid_out [100]       */
#define OF_BPC (OF_VD + K_OUT)         /* 410300: boxes_per_cls [100,151,4] */

// ---------------------------------------------------------------------------
// Single cooperative kernel, 4 phases separated by grid.sync():
//  A: softmax + box decode (blocks 0..149, one wave per proposal, barrier-free)
//  B: per-class greedy NMS (blocks 1..150 = class id), atomicMax fold into
//     packed[n] = (prob_bits<<32) | ~class  (max + argmax-first-tie exact)
//  C: block 0: bitonic top-100 over packed[600] (lax.top_k semantics),
//     write scores/labels/valid/final_boxes + top_idx/top_m
//  D: blocks 0..99 gather features rows; 100..199 gather boxes_per_cls rows
// LDS: 62 KB pool -> 2 blocks/CU; 200 blocks co-resident on 256 CUs.
// ---------------------------------------------------------------------------
__global__ __launch_bounds__(256) void fused_pp_kernel(
    const float* __restrict__ features, const float* __restrict__ logits,
    const float* __restrict__ breg, const float* __restrict__ pboxes,
    float* __restrict__ probs, float* __restrict__ boxes,
    unsigned long long* __restrict__ packed, int* __restrict__ top_idx,
    float* __restrict__ top_m, float* __restrict__ out) {
  cg::grid_group grid = cg::this_grid();
  int b = blockIdx.x;
  int t = threadIdx.x;

  __shared__ int s_m;
  // LDS pool (phase-aliased):
  //  B: [0,48000) keys(1024*8) then IoU mask (600*10*8); [48000,57600) boxes
  //     float4; [57600,58800) idx u16; [58800,59440) keep u8; [59440,61840) prob
  //  C: [0,8192) keys(1024*8); [8192,10592) score f32; [10592,12992) label i32
  alignas(16) __shared__ unsigned char pool[48000 + 9600 + 1280 + 640 + 2400];

  // ============================ Phase A: decode ============================
  {
    int wv = t >> 6, lane = t & 63;
    int n = b * 4 + wv;  // blocks 0..149 cover 600 proposals
    if (n < N_PROP) {
      const float* lg = logits + (size_t)n * NUM_CLS;
      int c0 = lane, c1 = lane + 64, c2 = lane + 128;
      float x0 = (c0 < NUM_CLS) ? lg[c0] : -INFINITY;
      float x1 = (c1 < NUM_CLS) ? lg[c1] : -INFINITY;
      float x2 = (c2 < NUM_CLS) ? lg[c2] : -INFINITY;

      float mx = fmaxf(fmaxf(x0, x1), x2);
      for (int off = 32; off > 0; off >>= 1) mx = fmaxf(mx, __shfl_xor(mx, off));

      float e0 = (c0 < NUM_CLS) ? expf(x0 - mx) : 0.0f;
      float e1 = (c1 < NUM_CLS) ? expf(x1 - mx) : 0.0f;
      float e2 = (c2 < NUM_CLS) ? expf(x2 - mx) : 0.0f;
      float sum = e0 + e1 + e2;
      for (int off = 32; off > 0; off >>= 1) sum += __shfl_xor(sum, off);

      float b0 = pboxes[n * 4 + 0], b1 = pboxes[n * 4 + 1];
      float b2 = pboxes[n * 4 + 2], b3 = pboxes[n * 4 + 3];
      float w = b2 - b0 + 1.0f, h = b3 - b1 + 1.0f;
      float cx = b0 + 0.5f * w, cy = b1 + 0.5f * h;

      float ee[3] = {e0, e1, e2};
      int cc[3] = {c0, c1, c2};
      for (int q = 0; q < 3; ++q) {
        int c = cc[q];
        if (c < NUM_CLS) {
          probs[(size_t)n * NUM_CLS + c] = ee[q] / sum;
          const float* d = breg + (size_t)n * (NUM_CLS * 4) + c * 4;
          float dx = d[0] / 10.0f, dy = d[1] / 10.0f;
          float dw = fminf(d[2] / 5.0f, BBOX_CLIP);
          float dh = fminf(d[3] / 5.0f, BBOX_CLIP);
          float pcx = dx * w + cx, pcy = dy * h + cy;
          float pw = expf(dw) * w, ph = expf(dh) * h;
          float xx1 = pcx - 0.5f * pw, yy1 = pcy - 0.5f * ph;
          float xx2 = pcx + 0.5f * pw - 1.0f, yy2 = pcy + 0.5f * ph - 1.0f;
          xx1 = fminf(fmaxf(xx1, 0.0f), IMG_W - 1.0f);
          yy1 = fminf(fmaxf(yy1, 0.0f), IMG_H - 1.0f);
          xx2 = fminf(fmaxf(xx2, 0.0f), IMG_W - 1.0f);
          yy2 = fminf(fmaxf(yy2, 0.0f), IMG_H - 1.0f);
          float4* bo = (float4*)(boxes + ((size_t)n * NUM_CLS + c) * 4);
          *bo = make_float4(xx1, yy1, xx2, yy2);
        }
      }
      if (lane == 0) packed[n] = 0x00000000FFFFFFFFULL;  // score 0.0, label 0
    }
  }
  grid.sync();

  // ============================ Phase B: NMS ==============================
  if (b >= 1 && b <= NUM_CLS - 1) {
    int j = b;  // class 1..150
    unsigned long long* s_key  = (unsigned long long*)pool;
    unsigned long long* s_mask = (unsigned long long*)pool;
    float4*             s_box  = (float4*)(pool + 48000);
    unsigned short*     s_idx  = (unsigned short*)(pool + 48000 + 9600);
    unsigned char*      s_keep = pool + 48000 + 9600 + 1280;
    float*              s_prob = (float*)(pool + 48000 + 9600 + 1280 + 640);

    if (t == 0) s_m = 0;
    __syncthreads();
    for (int n = t; n < N_PROP; n += 256) {
      float p = probs[(size_t)n * NUM_CLS + j];
      if (p > SCORE_THRESH) {
        int pos = atomicAdd(&s_m, 1);
        // score desc, index asc when sorted ascending (scores positive)
        s_key[pos] = ((unsigned long long)(~__float_as_uint(p)) << 32) | (unsigned)n;
      }
    }
    __syncthreads();
    int m = s_m;
    if (m > 0) {
      int sz = 1;
      while (sz < m) sz <<= 1;
      for (int i = m + t; i < sz; i += 256) s_key[i] = ~0ULL;
      __syncthreads();

      for (int k = 2; k <= sz; k <<= 1) {
        for (int len = k >> 1; len > 0; len >>= 1) {
          for (int i = t; i < sz; i += 256) {
            int p2 = i ^ len;
            if (p2 > i) {
              unsigned long long a = s_key[i], bb = s_key[p2];
              bool up = ((i & k) == 0);
              if ((a > bb) == up) { s_key[i] = bb; s_key[p2] = a; }
            }
          }
          __syncthreads();
        }
      }

      for (int i = t; i < m; i += 256) {
        unsigned long long k = s_key[i];
        int n = (int)(k & 0xFFFFFFFFULL);
        s_idx[i] = (unsigned short)n;
        s_prob[i] = __uint_as_float(~(unsigned)(k >> 32));
        s_box[i] = *(const float4*)(boxes + ((size_t)n * NUM_CLS + j) * 4);
      }
      __syncthreads();  // mask writes may clobber key region after this

      int words = (m + 63) >> 6;
      int wave = t >> 6, lane = t & 63;
      for (int i = wave; i < m; i += 4) {
        float4 bi = s_box[i];
        float ai = (bi.z - bi.x + 1.0f) * (bi.w - bi.y + 1.0f);
        for (int w = 0; w < words; ++w) {
          int jj = (w << 6) + lane;
          bool over = false;
          if (jj < m) {
            float4 bj = s_box[jj];
            float xx1 = fmaxf(bi.x, bj.x), yy1 = fmaxf(bi.y, bj.y);
            float xx2 = fminf(bi.z, bj.z), yy2 = fminf(bi.w, bj.w);
            float iw = fmaxf(xx2 - xx1 + 1.0f, 0.0f);
            float ih = fmaxf(yy2 - yy1 + 1.0f, 0.0f);
            float inter = iw * ih;
            float aj = (bj.z - bj.x + 1.0f) * (bj.w - bj.y + 1.0f);
            over = (inter / (ai + aj - inter)) > NMS_THRESH;
          }
          unsigned long long bal = __ballot(over);
          if (lane == 0) s_mask[(size_t)i * words + w] = bal;
        }
      }
      __syncthreads();

      if (t == 0) {
        unsigned long long removed[MAXW];
        for (int w = 0; w < words; ++w) removed[w] = 0ULL;
        int cnt = 0;
        for (int i = 0; i < m; ++i) {
          if (!((removed[i >> 6] >> (i & 63)) & 1ULL)) {
            ++cnt;
            s_keep[i] = (cnt <= PER_CLS_TOPN) ? 1 : 0;
            const unsigned long long* row = s_mask + (size_t)i * words;
            for (int w = 0; w < words; ++w) removed[w] |= row[w];
          } else {
            s_keep[i] = 0;
          }
        }
      }
      __syncthreads();
      for (int i = t; i < m; i += 256) {
        if (s_keep[i]) {
          unsigned long long key =
              ((unsigned long long)__float_as_uint(s_prob[i]) << 32) |
              (unsigned)(0xFFFFFFFFu - (unsigned)j);
          atomicMax(&packed[s_idx[i]], key);
        }
      }
    }
  }
  grid.sync();

  // ========================== Phase C: finalize ===========================
  if (b == 0) {
    unsigned long long* s_key = (unsigned long long*)pool;
    float* s_score = (float*)(pool + 8192);
    int*   s_label = (int*)(pool + 8192 + 2400);

    for (int n = t; n < 1024; n += 256) {
      if (n < N_PROP) {
        unsigned long long pk = packed[n];
        float best = __uint_as_float((unsigned)(pk >> 32));
        int lab = (int)(0xFFFFFFFFu - (unsigned)(pk & 0xFFFFFFFFULL));
        s_score[n] = best;
        s_label[n] = lab;
        float sel = (best > 0.0f) ? best : -1.0f;
        unsigned int sb = __float_as_uint(sel);
        unsigned int mapped = (sb >> 31) ? ~sb : (sb | 0x80000000u);  // sortable
        s_key[n] = ((unsigned long long)(~mapped) << 32) | (unsigned)n;
      } else {
        s_key[n] = ~0ULL;
      }
    }
    __syncthreads();

    for (int k = 2; k <= 1024; k <<= 1) {
      for (int len = k >> 1; len > 0; len >>= 1) {
        for (int i = t; i < 1024; i += 256) {
          int p2 = i ^ len;
          if (p2 > i) {
            unsigned long long a = s_key[i], bb = s_key[p2];
            bool up = ((i & k) == 0);
            if ((a > bb) == up) { s_key[i] = bb; s_key[p2] = a; }
          }
        }
        __syncthreads();
      }
    }

    if (t < K_OUT) {
      int n = (int)(s_key[t] & 0xFFFFFFFFULL);
      float v = s_score[n];
      bool valid = v > 0.0f;
      float mm = valid ? 1.0f : 0.0f;
      int glab = s_label[n];
      out[OF_SC + t] = valid ? v : 0.0f;
      out[OF_LB + t] = (float)(valid ? glab : 0);
      out[OF_VD + t] = mm;
      const float* bp = boxes + ((size_t)n * NUM_CLS + glab) * 4;
      out[OF_BOX + t * 4 + 0] = bp[0] * mm;
      out[OF_BOX + t * 4 + 1] = bp[1] * mm;
      out[OF_BOX + t * 4 + 2] = bp[2] * mm;
      out[OF_BOX + t * 4 + 3] = bp[3] * mm;
      top_idx[t] = n;
      top_m[t] = mm;
    }
  }
  grid.sync();

  // =========================== Phase D: gathers ===========================
  if (b < K_OUT) {
    int k = b;
    int n = top_idx[k];
    float mm = top_m[k];
    const float4* src = (const float4*)(features + (size_t)n * FEAT_DIM);
    float4* dst = (float4*)(out + (size_t)k * FEAT_DIM);
    for (int i = t; i < FEAT_DIM / 4; i += 256) {
      float4 v = src[i];
      dst[i] = make_float4(v.x * mm, v.y * mm, v.z * mm, v.w * mm);
    }
  } else {
    int k = b - K_OUT;
    int n = top_idx[k];
    float mm = top_m[k];
    const float4* src = (const float4*)(boxes + (size_t)n * NUM_CLS * 4);
    float4* dst = (float4*)(out + OF_BPC + (size_t)k * NUM_CLS * 4);
    for (int c = t; c < NUM_CLS; c += 256) {
      float4 v = src[c];
      dst[c] = make_float4(v.x * mm, v.y * mm, v.z * mm, v.w * mm);
    }
  }
}

extern "C" void kernel_launch(void* const* d_in, const int* in_sizes, int n_in,
                              void* d_out, int out_size, void* d_ws, size_t ws_size,
                              hipStream_t stream) {
  const float* features = (const float*)d_in[0];
  const float* logits   = (const float*)d_in[1];
  const float* breg     = (const float*)d_in[2];
  const float* pboxes   = (const float*)d_in[3];
  float* out = (float*)d_out;

  // workspace layout (16B-aligned chunks)
  float* probs = (float*)d_ws;                                   // 600*151 f32
  float* boxes = probs + N_PROP * NUM_CLS;                       // 600*151*4 f32
  unsigned long long* packed =
      (unsigned long long*)(boxes + (size_t)N_PROP * NUM_CLS * 4);  // 600 u64
  int*   top_idx = (int*)(packed + N_PROP);                      // 128 i32
  float* top_m   = (float*)(top_idx + 128);                      // 128 f32

  void* args[] = {(void*)&features, (void*)&logits, (void*)&breg,
                  (void*)&pboxes,   (void*)&probs,  (void*)&boxes,
                  (void*)&packed,   (void*)&top_idx, (void*)&top_m,
                  (void*)&out};
  hipLaunchCooperativeKernel((const void*)fused_pp_kernel, dim3(NBLK),
                             dim3(256), args, 0, stream);
}